// Round 10
// baseline (130.537 us; speedup 1.0000x reference)
//
#include <hip/hip_runtime.h>
#include <cstddef>
#include <cstdint>

typedef __attribute__((ext_vector_type(8))) _Float16 half8;
typedef __attribute__((ext_vector_type(4))) float f32x4;

constexpr int Bsz = 2048, Tsz = 120, Ksz = 128;
constexpr float L2E = 1.44269504088896340736f;  // log2(e)
constexpr float LN2 = 0.69314718055994530942f;  // ln(2)

__device__ __forceinline__ int expbits(float x) {
  return (int)(__float_as_uint(x) >> 23) - 127;   // floor(log2 x), x > 0
}

// drain own LDS ops -> barrier; compiler memory clobbers on both sides but
// NO sched_barrier: let exps/global-loads float into the wait shadows.
#define BAR() do {                                        \
    asm volatile("s_waitcnt lgkmcnt(0)" ::: "memory");    \
    __builtin_amdgcn_s_barrier();                         \
    asm volatile("" ::: "memory");                        \
  } while (0)

// 2 waves x 16 batches per block. Wave w owns states [64w, 64w+64) (4 tiles).
// Linear-space recursion: alpha*log2e = nReg + log2(P); per step
//   S = E^T.P (16 MFMAs/wave), P' = S * eem * 2^-Df, Df = expbits(maxcol P)+8.
// eem = exp(em_t) is computed one step AHEAD from a raw load issued 2+ steps
// earlier, so the in-step path has zero transcendentals and no vmcnt stalls.
__global__ __launch_bounds__(128, 1) void crf_fwd(
    const float* __restrict__ emis,   // [B,T,K]
    const int* __restrict__ tag,      // [B,T]
    const int* __restrict__ maskg,    // [B,T]
    const float* __restrict__ Tg,     // [K,K]
    float* __restrict__ nll)          // [B]
{
  __shared__ __align__(16) uint2 Pb[2][16 * 32];   // P f16 [col][state/4], dbuf
  __shared__ __align__(16) float lamp[2][16][10];  // 8 slots + pad (stride 10)
  __shared__ int maskLds[Tsz * 16];                // [t][c]

  const int tid = threadIdx.x;
  const int w = tid >> 6, lane = tid & 63;
  const int c = lane & 15, hi = lane >> 4;
  const int b0 = blockIdx.x * 16;
  const int sw2 = (c & 7) << 1;                    // XOR swizzle, uint2 units
  const int slot = 4 * w + hi;                     // 0..7

  const int soff = 64 * w + 4 * hi;
  const float* ep = emis + (size_t)(b0 + c) * Tsz * Ksz + soff;

  // issue t=0..3 emission loads up front (16 dwordx4)
  f32x4 a0[4], rT[4], rA[4], rB[4];
  #pragma unroll
  for (int qq = 0; qq < 4; ++qq) a0[qq] = *(const f32x4*)(ep + 16 * qq);
  #pragma unroll
  for (int qq = 0; qq < 4; ++qq) rT[qq] = *(const f32x4*)(ep + Ksz + 16 * qq);
  #pragma unroll
  for (int qq = 0; qq < 4; ++qq) rA[qq] = *(const f32x4*)(ep + 2 * Ksz + 16 * qq);
  #pragma unroll
  for (int qq = 0; qq < 4; ++qq) rB[qq] = *(const f32x4*)(ep + 3 * Ksz + 16 * qq);

  // stage masks
  for (int i = tid; i < Tsz * 16; i += 128) {
    int cc = i & 15, tt = i >> 4;
    maskLds[i] = maskg[(size_t)(b0 + cc) * Tsz + tt];
  }

  // E^T A-fragments from global (L2-hot, one-time):
  // Ef[qq][m][j] = exp(T[32m+8hi+j][64w+16qq+c])
  half8 Ef[4][4];
  #pragma unroll
  for (int qq = 0; qq < 4; ++qq)
    #pragma unroll
    for (int m = 0; m < 4; ++m) {
      half8 v;
      #pragma unroll
      for (int j = 0; j < 8; ++j)
        v[j] = (_Float16)__expf(Tg[(size_t)(32 * m + 8 * hi + j) * Ksz + 64 * w + 16 * qq + c]);
      Ef[qq][m] = v;
    }

  // ---- prologue: per-col max of alpha0 via lamp[1] scratch
  {
    float pm = -3.0e38f;
    #pragma unroll
    for (int qq = 0; qq < 4; ++qq)
      #pragma unroll
      for (int r = 0; r < 4; ++r) pm = fmaxf(pm, a0[qq][r]);
    lamp[1][c][slot] = pm;
  }
  BAR();
  float nReg;
  f32x4 Pv[4], eemA[4], eemB[4];
  {
    const float* lr = &lamp[1][c][0];
    f32x4 l0 = *(const f32x4*)(lr), l1 = *(const f32x4*)(lr + 4);
    f32x4 mm;
    #pragma unroll
    for (int r = 0; r < 4; ++r) mm[r] = fmaxf(l0[r], l1[r]);
    float mx = fmaxf(fmaxf(mm[0], mm[1]), fmaxf(mm[2], mm[3]));
    nReg = mx * L2E;
    #pragma unroll
    for (int qq = 0; qq < 4; ++qq)
      #pragma unroll
      for (int r = 0; r < 4; ++r) Pv[qq][r] = __expf(a0[qq][r] - mx);
    #pragma unroll
    for (int qq = 0; qq < 4; ++qq)
      #pragma unroll
      for (int r = 0; r < 4; ++r) eemA[qq][r] = __expf(rT[qq][r]);   // exp(em_1)
  }

  auto publish = [&](int wr) {
    float pl = 0.f;
    #pragma unroll
    for (int qq = 0; qq < 4; ++qq) {
      union { _Float16 h[4]; uint2 u; } pk;
      #pragma unroll
      for (int r = 0; r < 4; ++r) {
        pk.h[r] = (_Float16)Pv[qq][r];
        pl = fmaxf(pl, Pv[qq][r]);
      }
      Pb[wr][c * 32 + ((16 * w + 4 * qq + hi) ^ sw2)] = pk.u;
    }
    lamp[wr][c][slot] = pl;
  };

  publish(0);
  BAR();

  const f32x4 z = {0.f, 0.f, 0.f, 0.f};

  auto STEP = [&](int t, f32x4 (&eemC)[4]) {
    const int rd = (t - 1) & 1, wr = t & 1;
    const uint2* prowR = &Pb[rd][c * 32];
    half8 bf[4];
    #pragma unroll
    for (int m = 0; m < 4; ++m) {
      union { uint4 u4; half8 h; } rb;
      rb.u4 = *(const uint4*)(&prowR[(8 * m + 2 * hi) ^ sw2]);
      bf[m] = rb.h;
    }
    const float* lr = &lamp[rd][c][0];
    f32x4 l0 = *(const f32x4*)(lr), l1 = *(const f32x4*)(lr + 4);
    f32x4 mm;
    #pragma unroll
    for (int r = 0; r < 4; ++r) mm[r] = fmaxf(l0[r], l1[r]);
    const float lam = fmaxf(fmaxf(mm[0], mm[1]), fmaxf(mm[2], mm[3]));
    const int Dfi = expbits(lam) + 8;
    const float s2 = __uint_as_float((uint32_t)(127 - Dfi) << 23);  // exact 2^-Df
    const int mt = maskLds[t * 16 + c];

    f32x4 c2[4];
    #pragma unroll
    for (int qq = 0; qq < 4; ++qq)
      #pragma unroll
      for (int r = 0; r < 4; ++r) c2[qq][r] = eemC[qq][r] * s2;

    f32x4 acc[4];
    #pragma unroll
    for (int qq = 0; qq < 4; ++qq) {
      f32x4 aA = __builtin_amdgcn_mfma_f32_16x16x32_f16(
          Ef[qq][1], bf[1],
          __builtin_amdgcn_mfma_f32_16x16x32_f16(Ef[qq][0], bf[0], z, 0, 0, 0),
          0, 0, 0);
      f32x4 aB = __builtin_amdgcn_mfma_f32_16x16x32_f16(
          Ef[qq][3], bf[3],
          __builtin_amdgcn_mfma_f32_16x16x32_f16(Ef[qq][2], bf[2], z, 0, 0, 0),
          0, 0, 0);
      #pragma unroll
      for (int r = 0; r < 4; ++r) acc[qq][r] = aA[r] + aB[r];
    }

    unsigned long long bal = __ballot(mt > 0);
    if (bal == ~0ull) {
      #pragma unroll
      for (int qq = 0; qq < 4; ++qq)
        #pragma unroll
        for (int r = 0; r < 4; ++r) Pv[qq][r] = acc[qq][r] * c2[qq][r];
    } else {
      #pragma unroll
      for (int qq = 0; qq < 4; ++qq)
        #pragma unroll
        for (int r = 0; r < 4; ++r) {
          float pn = acc[qq][r] * c2[qq][r];
          float po = Pv[qq][r] * s2;
          Pv[qq][r] = (mt > 0) ? pn : po;
        }
    }
    nReg += (float)Dfi;

    publish(wr);
    BAR();
  };

  // pair loop; invariant at entry: eemA=exp(em_t), rA=em_{t+1}, rB=em_{t+2}
  #pragma unroll 1
  for (int t = 1; t <= Tsz - 3; t += 2) {   // 1,3,...,117
    #pragma unroll
    for (int qq = 0; qq < 4; ++qq)
      #pragma unroll
      for (int r = 0; r < 4; ++r) eemB[qq][r] = __expf(rA[qq][r]);  // exp(em_{t+1})
    STEP(t, eemA);
    if (t + 3 < Tsz) {
      #pragma unroll
      for (int qq = 0; qq < 4; ++qq)
        rA[qq] = *(const f32x4*)(ep + (size_t)(t + 3) * Ksz + 16 * qq);
    }
    #pragma unroll
    for (int qq = 0; qq < 4; ++qq)
      #pragma unroll
      for (int r = 0; r < 4; ++r) eemA[qq][r] = __expf(rB[qq][r]);  // exp(em_{t+2})
    STEP(t + 1, eemB);
    if (t + 4 < Tsz) {
      #pragma unroll
      for (int qq = 0; qq < 4; ++qq)
        rB[qq] = *(const f32x4*)(ep + (size_t)(t + 4) * Ksz + 16 * qq);
    }
  }
  STEP(Tsz - 1, eemA);                      // t = 119, eemA = exp(em_119)

  // ---- lognorm = nReg*ln2 + log(sum_col P)  (shared normalizer -> no max)
  {
    float ss = 0.f;
    #pragma unroll
    for (int qq = 0; qq < 4; ++qq)
      #pragma unroll
      for (int r = 0; r < 4; ++r) ss += Pv[qq][r];
    lamp[0][c][slot] = ss;   // buffer 0 no longer read
  }
  BAR();
  float lognorm;
  {
    const float* lr = &lamp[0][c][0];
    f32x4 l0 = *(const f32x4*)(lr), l1 = *(const f32x4*)(lr + 4);
    float tot = ((l0[0] + l0[1]) + (l0[2] + l0[3]))
              + ((l1[0] + l1[1]) + (l1[2] + l1[3]));
    lognorm = nReg * LN2 + __logf(tot);
  }

  // ---- score: slot s handles t in [15s, 15s+15) for batch c
  {
    const int* tb = tag + (size_t)(b0 + c) * Tsz;
    const float* eb2 = emis + (size_t)(b0 + c) * Tsz * Ksz;
    float sc = 0.f;
    const int t0 = 15 * slot, t1 = t0 + 15;
    #pragma unroll 1
    for (int t = t0; t < t1; ++t) {
      int tg0 = tb[t];
      float m0 = (float)maskLds[t * 16 + c];
      sc += eb2[(size_t)t * Ksz + tg0] * m0;
      if (t + 1 < Tsz) {
        int tg1 = tb[t + 1];
        sc += Tg[(size_t)tg0 * Ksz + tg1] * m0 * (float)maskLds[(t + 1) * 16 + c];
      }
    }
    float* scb = (float*)&Pb[0][0];   // reuse as [c][8]
    scb[c * 8 + slot] = sc;
    BAR();
    if (tid < 16) {                   // w=0, hi=0, c=tid
      const float* sr = &scb[c * 8];
      float s2r = 0.f;
      #pragma unroll
      for (int s = 0; s < 8; ++s) s2r += sr[s];
      nll[b0 + c] = lognorm - s2r;
    }
  }
}

// deterministic fixed-order mean over B values
__global__ __launch_bounds__(256) void crf_reduce(
    const float* __restrict__ nll, float* __restrict__ out) {
  __shared__ float buf[256];
  float s = 0.f;
  for (int i = threadIdx.x; i < Bsz; i += 256) s += nll[i];
  buf[threadIdx.x] = s;
  __syncthreads();
  #pragma unroll
  for (int off = 128; off > 0; off >>= 1) {
    if (threadIdx.x < off) buf[threadIdx.x] += buf[threadIdx.x + off];
    __syncthreads();
  }
  if (threadIdx.x == 0) out[0] = buf[0] / (float)Bsz;
}

extern "C" void kernel_launch(void* const* d_in, const int* in_sizes, int n_in,
                              void* d_out, int out_size, void* d_ws, size_t ws_size,
                              hipStream_t stream) {
  const float* emissions   = (const float*)d_in[0];
  const int*   tag_ids     = (const int*)d_in[1];
  const int*   mask        = (const int*)d_in[2];
  const float* transitions = (const float*)d_in[3];

  float* nll = (float*)d_ws;  // 2048 floats

  crf_fwd<<<Bsz / 16, 128, 0, stream>>>(emissions, tag_ids, mask, transitions, nll);
  crf_reduce<<<1, 256, 0, stream>>>(nll, (float*)d_out);
}

// Round 12
// 110.939 us; speedup vs baseline: 1.1767x; 1.1767x over previous
//
#include <hip/hip_runtime.h>
#include <hip/hip_bf16.h>
#include <cstddef>
#include <cstdint>

typedef __attribute__((ext_vector_type(8))) short short8;  // 8 bf16 in 4 VGPRs
typedef __attribute__((ext_vector_type(4))) float f32x4;

constexpr int Bsz = 2048, Tsz = 120, Ksz = 128;
constexpr int BPB = 4;                          // real batches/block -> 512 blocks
constexpr float L2E = 1.44269504088896340736f;  // log2(e)
constexpr float LN2 = 0.69314718055994530942f;  // ln(2)

__device__ __forceinline__ int expbits(float x) {
  return (int)(__float_as_uint(x) >> 23) - 127;   // floor(log2 x), x > 0
}

// drain own LDS ops -> barrier; memory clobbers, no sched pin.
#define BAR() do {                                        \
    asm volatile("s_waitcnt lgkmcnt(0)" ::: "memory");    \
    __builtin_amdgcn_s_barrier();                         \
    asm volatile("" ::: "memory");                        \
  } while (0)

// 4 waves x 4 real batches (16 MFMA cols = 4 batches x 4 mirrors), 512 blocks
// -> 2 co-resident blocks/CU hide each other's barrier/LDS latency.
// P is bf16 in LDS. Linear-space recursion: alpha*log2e = nReg + log2(P);
//   S = E^T.P (MFMA), P' = S * exp(em) * 2^-Df.
// NORMALIZER (stable, zero critical-path cost): Df_t = 7 + (z_{t-2} >> 2),
// where z is expbits(max_col P) from the lamp exchange read ONE step earlier
// (2-stale). Gain-1/4 delayed feedback -> poles at 0.5 (vs r5/r6's unit-gain
// oscillator) -> z settles at ~4*(g-7), bf16 absorbs the +-binade noise.
// So Df/s2/c2 are known BEFORE the step: post-MFMA is 8 muls + pack only.
__global__ __launch_bounds__(256) void crf_fwd(
    const float* __restrict__ emis,   // [B,T,K]
    const int* __restrict__ tag,      // [B,T]
    const int* __restrict__ maskg,    // [B,T]
    const float* __restrict__ Tg,     // [K,K]
    float* __restrict__ nll)          // [B]
{
  __shared__ __align__(16) uint2 Pb[2][16 * 32];   // P bf16 [col][state/4], dbuf
  __shared__ __align__(16) float lamp[2][16][20];  // per-(w,hi) partial maxes
  __shared__ int maskLds[Tsz * BPB];               // [t][bc]

  const int tid = threadIdx.x;
  const int w = tid >> 6, lane = tid & 63;
  const int c = lane & 15, hi = lane >> 4;
  const int bc = c & (BPB - 1);
  const int b0 = blockIdx.x * BPB;
  const int sw2 = (c & 7) << 1;                    // XOR swizzle, uint2 units
  const int slot = 4 * w + hi;                     // 0..15

  const int soff = 32 * w + 4 * hi;
  const float* ep = emis + (size_t)(b0 + bc) * Tsz * Ksz + soff;

  // issue t=0..3 emission loads early
  f32x4 a0[2], r1[2], rA[2], rB[2];
  a0[0] = *(const f32x4*)(ep);           a0[1] = *(const f32x4*)(ep + 16);
  r1[0] = *(const f32x4*)(ep + Ksz);     r1[1] = *(const f32x4*)(ep + Ksz + 16);
  rA[0] = *(const f32x4*)(ep + 2 * Ksz); rA[1] = *(const f32x4*)(ep + 2 * Ksz + 16);
  rB[0] = *(const f32x4*)(ep + 3 * Ksz); rB[1] = *(const f32x4*)(ep + 3 * Ksz + 16);

  // stage masks
  for (int i = tid; i < Tsz * BPB; i += 256) {
    int bb = i & (BPB - 1), tt = i >> 2;
    maskLds[i] = maskg[(size_t)(b0 + bb) * Tsz + tt];
  }

  // E^T A-fragments from global (L2-hot, no LDS stage -- r9's staging was the
  // bank-conflict hotspot): Ef[rti][m][j] = bf16(exp(T[32m+8hi+j][32w+16rti+c]))
  short8 Ef[2][4];
  #pragma unroll
  for (int rti = 0; rti < 2; ++rti)
    #pragma unroll
    for (int m = 0; m < 4; ++m) {
      short8 v;
      #pragma unroll
      for (int j = 0; j < 8; ++j) {
        union { __hip_bfloat16 h; short s; } cv;
        cv.h = __float2bfloat16(
            __expf(Tg[(size_t)(32 * m + 8 * hi + j) * Ksz + 32 * w + 16 * rti + c]));
        v[j] = cv.s;
      }
      Ef[rti][m] = v;
    }

  // ---- prologue: per-col max of alpha0 -> mx
  {
    float pm = fmaxf(fmaxf(fmaxf(a0[0][0], a0[0][1]), fmaxf(a0[0][2], a0[0][3])),
                     fmaxf(fmaxf(a0[1][0], a0[1][1]), fmaxf(a0[1][2], a0[1][3])));
    lamp[1][c][slot] = pm;
  }
  BAR();
  float nReg;
  f32x4 Pv[2];
  {
    const float* lr = &lamp[1][c][0];
    f32x4 l0 = *(const f32x4*)(lr), l1 = *(const f32x4*)(lr + 4);
    f32x4 l2 = *(const f32x4*)(lr + 8), l3 = *(const f32x4*)(lr + 12);
    f32x4 mm;
    #pragma unroll
    for (int r = 0; r < 4; ++r) mm[r] = fmaxf(fmaxf(l0[r], l1[r]), fmaxf(l2[r], l3[r]));
    float mx = fmaxf(fmaxf(mm[0], mm[1]), fmaxf(mm[2], mm[3]));
    nReg = mx * L2E;
    #pragma unroll
    for (int rti = 0; rti < 2; ++rti)
      #pragma unroll
      for (int r = 0; r < 4; ++r) Pv[rti][r] = __expf(a0[rti][r] - mx);  // max=1
  }

  auto publish = [&](int wr) {
    float pl = 0.f;
    #pragma unroll
    for (int rti = 0; rti < 2; ++rti) {
      union { __hip_bfloat16 h[4]; uint2 u; } pk;
      #pragma unroll
      for (int r = 0; r < 4; ++r) {
        pk.h[r] = __float2bfloat16(Pv[rti][r]);
        pl = fmaxf(pl, Pv[rti][r]);
      }
      Pb[wr][c * 32 + ((8 * w + 4 * rti + hi) ^ sw2)] = pk.u;
    }
    lamp[wr][c][slot] = pl;
  };

  publish(0);
  BAR();

  const f32x4 z4 = {0.f, 0.f, 0.f, 0.f};

  // STEP t: uses pre-scaled c2 = exp(em_t)*2^-Df_t and s2 = 2^-Df_t (both
  // known at entry); returns z_{t-1} = expbits(max P_{t-1}) for Df_{t+1}.
  auto STEP = [&](int t, const f32x4 (&c2)[2], float s2, int Dfi, int& zOut) {
    const int rd = (t - 1) & 1, wr = t & 1;
    const uint2* prowR = &Pb[rd][c * 32];
    short8 bf[4];
    #pragma unroll
    for (int m = 0; m < 4; ++m) {
      union { uint4 u4; short8 h; } rb;
      rb.u4 = *(const uint4*)(&prowR[(8 * m + 2 * hi) ^ sw2]);
      bf[m] = rb.h;
    }
    // lamp fold: result needed only NEXT step -> pure shadow work
    const float* lr = &lamp[rd][c][0];
    f32x4 l0 = *(const f32x4*)(lr), l1 = *(const f32x4*)(lr + 4);
    f32x4 l2 = *(const f32x4*)(lr + 8), l3 = *(const f32x4*)(lr + 12);
    const int mt = maskLds[t * BPB + bc];

    f32x4 acc[2];
    #pragma unroll
    for (int rti = 0; rti < 2; ++rti) {
      f32x4 aA = __builtin_amdgcn_mfma_f32_16x16x32_bf16(
          Ef[rti][1], bf[1],
          __builtin_amdgcn_mfma_f32_16x16x32_bf16(Ef[rti][0], bf[0], z4, 0, 0, 0),
          0, 0, 0);
      f32x4 aB = __builtin_amdgcn_mfma_f32_16x16x32_bf16(
          Ef[rti][3], bf[3],
          __builtin_amdgcn_mfma_f32_16x16x32_bf16(Ef[rti][2], bf[2], z4, 0, 0, 0),
          0, 0, 0);
      #pragma unroll
      for (int r = 0; r < 4; ++r) acc[rti][r] = aA[r] + aB[r];
    }

    f32x4 mm;
    #pragma unroll
    for (int r = 0; r < 4; ++r) mm[r] = fmaxf(fmaxf(l0[r], l1[r]), fmaxf(l2[r], l3[r]));
    zOut = expbits(fmaxf(fmaxf(mm[0], mm[1]), fmaxf(mm[2], mm[3])));

    unsigned long long bal = __ballot(mt > 0);
    if (bal == ~0ull) {
      #pragma unroll
      for (int rti = 0; rti < 2; ++rti)
        #pragma unroll
        for (int r = 0; r < 4; ++r) Pv[rti][r] = acc[rti][r] * c2[rti][r];
    } else {
      #pragma unroll
      for (int rti = 0; rti < 2; ++rti)
        #pragma unroll
        for (int r = 0; r < 4; ++r) {
          float pn = acc[rti][r] * c2[rti][r];
          float po = Pv[rti][r] * s2;       // alpha held: P scales by 2^-Df
          Pv[rti][r] = (mt > 0) ? pn : po;
        }
    }
    nReg += (float)Dfi;

    publish(wr);
    BAR();
  };

  // controller state: Df_1 = 7 (z_{-1}:=0, maxP0=1)
  int DfA = 7;
  float s2A = __uint_as_float((uint32_t)(127 - 7) << 23);
  f32x4 c2A[2], c2B[2];
  #pragma unroll
  for (int rti = 0; rti < 2; ++rti)
    #pragma unroll
    for (int r = 0; r < 4; ++r) c2A[rti][r] = __expf(r1[rti][r]) * s2A;

  int zCur;
  #pragma unroll 1
  for (int t = 1; t <= Tsz - 3; t += 2) {   // 1,3,...,117
    // eem for t+1 (raw exp; scaled after STEP(t) reveals z_{t-1})
    f32x4 eB[2];
    #pragma unroll
    for (int rti = 0; rti < 2; ++rti)
      #pragma unroll
      for (int r = 0; r < 4; ++r) eB[rti][r] = __expf(rA[rti][r]);
    STEP(t, c2A, s2A, DfA, zCur);
    int DfB = 7 + (zCur >> 2);
    DfB = DfB < -90 ? -90 : (DfB > 110 ? 110 : DfB);
    float s2B = __uint_as_float((uint32_t)(127 - DfB) << 23);
    #pragma unroll
    for (int rti = 0; rti < 2; ++rti)
      #pragma unroll
      for (int r = 0; r < 4; ++r) c2B[rti][r] = eB[rti][r] * s2B;
    if (t + 3 < Tsz) {
      rA[0] = *(const f32x4*)(ep + (size_t)(t + 3) * Ksz);
      rA[1] = *(const f32x4*)(ep + (size_t)(t + 3) * Ksz + 16);
    }

    f32x4 eA[2];
    #pragma unroll
    for (int rti = 0; rti < 2; ++rti)
      #pragma unroll
      for (int r = 0; r < 4; ++r) eA[rti][r] = __expf(rB[rti][r]);
    STEP(t + 1, c2B, s2B, DfB, zCur);
    DfA = 7 + (zCur >> 2);
    DfA = DfA < -90 ? -90 : (DfA > 110 ? 110 : DfA);
    s2A = __uint_as_float((uint32_t)(127 - DfA) << 23);
    #pragma unroll
    for (int rti = 0; rti < 2; ++rti)
      #pragma unroll
      for (int r = 0; r < 4; ++r) c2A[rti][r] = eA[rti][r] * s2A;
    if (t + 4 < Tsz) {
      rB[0] = *(const f32x4*)(ep + (size_t)(t + 4) * Ksz);
      rB[1] = *(const f32x4*)(ep + (size_t)(t + 4) * Ksz + 16);
    }
  }
  STEP(Tsz - 1, c2A, s2A, DfA, zCur);       // t = 119

  // ---- lognorm = nReg*ln2 + ln(sum_col P)
  {
    float ss = ((Pv[0][0] + Pv[0][1]) + (Pv[0][2] + Pv[0][3]))
             + ((Pv[1][0] + Pv[1][1]) + (Pv[1][2] + Pv[1][3]));
    lamp[0][c][slot] = ss;    // buffer 0 dead after last step (wr was 1)
  }
  BAR();
  float lognorm;
  {
    const float* lr = &lamp[0][c][0];
    f32x4 l0 = *(const f32x4*)(lr), l1 = *(const f32x4*)(lr + 4);
    f32x4 l2 = *(const f32x4*)(lr + 8), l3 = *(const f32x4*)(lr + 12);
    float tot = (((l0[0] + l0[1]) + (l0[2] + l0[3]))
              + ((l1[0] + l1[1]) + (l1[2] + l1[3])))
              + (((l2[0] + l2[1]) + (l2[2] + l2[3]))
              + ((l3[0] + l3[1]) + (l3[2] + l3[3])));
    lognorm = nReg * LN2 + __logf(tot);
  }

  // ---- score: slot s covers t in [8s, 8s+8), batch bc (mirrors duplicate)
  {
    const int* tb = tag + (size_t)(b0 + bc) * Tsz;
    const float* eb2 = emis + (size_t)(b0 + bc) * Tsz * Ksz;
    float sc = 0.f;
    const int t0 = 8 * slot;
    const int t1 = (t0 + 8 < Tsz) ? t0 + 8 : Tsz;
    #pragma unroll 1
    for (int t = t0; t < t1; ++t) {
      int tg0 = tb[t];
      float m0 = (float)maskLds[t * BPB + bc];
      sc += eb2[(size_t)t * Ksz + tg0] * m0;
      if (t + 1 < Tsz) {
        int tg1 = tb[t + 1];
        sc += Tg[(size_t)tg0 * Ksz + tg1] * m0 * (float)maskLds[(t + 1) * BPB + bc];
      }
    }
    float* scb = (float*)&Pb[0][0];   // reuse as [bc][16]
    scb[bc * 16 + slot] = sc;         // mirror cols write identical values
    BAR();
    if (tid < BPB) {                  // w=0, hi=0, c=tid (real batch)
      const float* sr = &scb[tid * 16];
      float s2r = 0.f;
      #pragma unroll
      for (int s = 0; s < 16; ++s) s2r += sr[s];
      nll[b0 + tid] = lognorm - s2r;
    }
  }
}

// deterministic fixed-order mean over B values
__global__ __launch_bounds__(256) void crf_reduce(
    const float* __restrict__ nll, float* __restrict__ out) {
  __shared__ float buf[256];
  float s = 0.f;
  for (int i = threadIdx.x; i < Bsz; i += 256) s += nll[i];
  buf[threadIdx.x] = s;
  __syncthreads();
  #pragma unroll
  for (int off = 128; off > 0; off >>= 1) {
    if (threadIdx.x < off) buf[threadIdx.x] += buf[threadIdx.x + off];
    __syncthreads();
  }
  if (threadIdx.x == 0) out[0] = buf[0] / (float)Bsz;
}

extern "C" void kernel_launch(void* const* d_in, const int* in_sizes, int n_in,
                              void* d_out, int out_size, void* d_ws, size_t ws_size,
                              hipStream_t stream) {
  const float* emissions   = (const float*)d_in[0];
  const int*   tag_ids     = (const int*)d_in[1];
  const int*   mask        = (const int*)d_in[2];
  const float* transitions = (const float*)d_in[3];

  float* nll = (float*)d_ws;  // 2048 floats

  crf_fwd<<<Bsz / BPB, 256, 0, stream>>>(emissions, tag_ids, mask, transitions, nll);
  crf_reduce<<<1, 256, 0, stream>>>(nll, (float*)d_out);
}

// Round 14
// 98.070 us; speedup vs baseline: 1.3311x; 1.1312x over previous
//
#include <hip/hip_runtime.h>
#include <hip/hip_bf16.h>
#include <cstddef>
#include <cstdint>

typedef __attribute__((ext_vector_type(8))) short short8;  // 8 bf16 in 4 VGPRs
typedef __attribute__((ext_vector_type(4))) float f32x4;

constexpr int Bsz = 2048, Tsz = 120, Ksz = 128;
constexpr float L2E = 1.44269504088896340736f;  // log2(e)
constexpr float LN2 = 0.69314718055994530942f;  // ln(2)

__device__ __forceinline__ int expbits(float x) {
  return (int)(__float_as_uint(x) >> 23) - 127;   // floor(log2 x), x > 0
}

// drain own LDS ops -> barrier; memory clobbers, no sched pin.
#define BAR() do {                                        \
    asm volatile("s_waitcnt lgkmcnt(0)" ::: "memory");    \
    __builtin_amdgcn_s_barrier();                         \
    asm volatile("" ::: "memory");                        \
  } while (0)

// r14 = r12's GREEN kernel (stale gain-1/4 controller + producer-side lamp)
// with ONLY the geometry changed to the best-measured one (r8/r9):
// 4 waves x 16 REAL batches per block, 128 blocks. Wave w owns states
// [32w,32w+32). P bf16 in LDS (f32-wide exponent range).
// Linear-space recursion: alpha*log2e = nReg + log2(P);
//   S = E^T.P (2x2 MFMA chains), P' = S * c2, c2 = exp(em)*2^-Df.
// Controller (r12-verified): Df_{t+1} = 7 + (z_{t-1} >> 2), z from lamp
// partial maxes of P (read at step t top, folded after MFMA -- shadow work).
// Poles at 0.5 -> no oscillation (r5/r6 lesson); bf16 absorbs excursions.
__global__ __launch_bounds__(256) void crf_fwd(
    const float* __restrict__ emis,   // [B,T,K]
    const int* __restrict__ tag,      // [B,T]
    const int* __restrict__ maskg,    // [B,T]
    const float* __restrict__ Tg,     // [K,K]
    float* __restrict__ nll)          // [B]
{
  __shared__ __align__(16) uint2 Pb[2][16 * 32];   // P bf16 [col][state/4], dbuf
  __shared__ __align__(16) float lamp[2][16][20];  // per-(w,hi) partial maxes
  __shared__ int maskLds[Tsz * 16];                // [t][c]

  const int tid = threadIdx.x;
  const int w = tid >> 6, lane = tid & 63;
  const int c = lane & 15, hi = lane >> 4;
  const int b0 = blockIdx.x * 16;
  const int sw2 = (c & 7) << 1;                    // XOR swizzle, uint2 units
  const int slot = 4 * w + hi;                     // 0..15

  const int soff = 32 * w + 4 * hi;
  const float* ep = emis + (size_t)(b0 + c) * Tsz * Ksz + soff;

  // issue t=0..3 emission loads early
  f32x4 a0[2], r1[2], rA[2], rB[2];
  a0[0] = *(const f32x4*)(ep);           a0[1] = *(const f32x4*)(ep + 16);
  r1[0] = *(const f32x4*)(ep + Ksz);     r1[1] = *(const f32x4*)(ep + Ksz + 16);
  rA[0] = *(const f32x4*)(ep + 2 * Ksz); rA[1] = *(const f32x4*)(ep + 2 * Ksz + 16);
  rB[0] = *(const f32x4*)(ep + 3 * Ksz); rB[1] = *(const f32x4*)(ep + 3 * Ksz + 16);

  // stage masks
  for (int i = tid; i < Tsz * 16; i += 256) {
    int cc = i & 15, tt = i >> 4;
    maskLds[i] = maskg[(size_t)(b0 + cc) * Tsz + tt];
  }

  // E^T A-fragments from global (L2-hot):
  // Ef[rti][m][j] = bf16(exp(T[32m+8hi+j][32w+16rti+c]))
  short8 Ef[2][4];
  #pragma unroll
  for (int rti = 0; rti < 2; ++rti)
    #pragma unroll
    for (int m = 0; m < 4; ++m) {
      short8 v;
      #pragma unroll
      for (int j = 0; j < 8; ++j) {
        union { __hip_bfloat16 h; short s; } cv;
        cv.h = __float2bfloat16(
            __expf(Tg[(size_t)(32 * m + 8 * hi + j) * Ksz + 32 * w + 16 * rti + c]));
        v[j] = cv.s;
      }
      Ef[rti][m] = v;
    }

  // ---- prologue: per-col max of alpha0 -> mx (lamp[1] scratch)
  {
    float pm = fmaxf(fmaxf(fmaxf(a0[0][0], a0[0][1]), fmaxf(a0[0][2], a0[0][3])),
                     fmaxf(fmaxf(a0[1][0], a0[1][1]), fmaxf(a0[1][2], a0[1][3])));
    lamp[1][c][slot] = pm;
  }
  BAR();
  float nReg;
  f32x4 Pv[2];
  {
    const float* lr = &lamp[1][c][0];
    f32x4 l0 = *(const f32x4*)(lr), l1 = *(const f32x4*)(lr + 4);
    f32x4 l2 = *(const f32x4*)(lr + 8), l3 = *(const f32x4*)(lr + 12);
    f32x4 mm;
    #pragma unroll
    for (int r = 0; r < 4; ++r) mm[r] = fmaxf(fmaxf(l0[r], l1[r]), fmaxf(l2[r], l3[r]));
    float mx = fmaxf(fmaxf(mm[0], mm[1]), fmaxf(mm[2], mm[3]));
    nReg = mx * L2E;
    #pragma unroll
    for (int rti = 0; rti < 2; ++rti)
      #pragma unroll
      for (int r = 0; r < 4; ++r) Pv[rti][r] = __expf(a0[rti][r] - mx);  // max=1
  }

  auto publish = [&](int wr) {
    float pl = 0.f;
    #pragma unroll
    for (int rti = 0; rti < 2; ++rti) {
      union { __hip_bfloat16 h[4]; uint2 u; } pk;
      #pragma unroll
      for (int r = 0; r < 4; ++r) {
        pk.h[r] = __float2bfloat16(Pv[rti][r]);
        pl = fmaxf(pl, Pv[rti][r]);
      }
      Pb[wr][c * 32 + ((8 * w + 4 * rti + hi) ^ sw2)] = pk.u;
    }
    lamp[wr][c][slot] = pl;
  };

  publish(0);
  BAR();

  const f32x4 z4 = {0.f, 0.f, 0.f, 0.f};

  // STEP t: c2 = exp(em_t)*2^-Df_t and s2 = 2^-Df_t known at entry;
  // zOut = expbits(max_col P_{t-1}) from lamp (folded after MFMA, shadow).
  auto STEP = [&](int t, const f32x4 (&c2)[2], float s2, int Dfi, int& zOut) {
    const int rd = (t - 1) & 1, wr = t & 1;
    const uint2* prowR = &Pb[rd][c * 32];
    short8 bf[4];
    #pragma unroll
    for (int m = 0; m < 4; ++m) {
      union { uint4 u4; short8 h; } rb;
      rb.u4 = *(const uint4*)(&prowR[(8 * m + 2 * hi) ^ sw2]);
      bf[m] = rb.h;
    }
    // lamp partials: issued with the bf reads; folded after MFMA
    const float* lr = &lamp[rd][c][0];
    f32x4 l0 = *(const f32x4*)(lr), l1 = *(const f32x4*)(lr + 4);
    f32x4 l2 = *(const f32x4*)(lr + 8), l3 = *(const f32x4*)(lr + 12);
    const int mt = maskLds[t * 16 + c];

    f32x4 acc[2];
    #pragma unroll
    for (int rti = 0; rti < 2; ++rti) {
      f32x4 aA = __builtin_amdgcn_mfma_f32_16x16x32_bf16(
          Ef[rti][1], bf[1],
          __builtin_amdgcn_mfma_f32_16x16x32_bf16(Ef[rti][0], bf[0], z4, 0, 0, 0),
          0, 0, 0);
      f32x4 aB = __builtin_amdgcn_mfma_f32_16x16x32_bf16(
          Ef[rti][3], bf[3],
          __builtin_amdgcn_mfma_f32_16x16x32_bf16(Ef[rti][2], bf[2], z4, 0, 0, 0),
          0, 0, 0);
      #pragma unroll
      for (int r = 0; r < 4; ++r) acc[rti][r] = aA[r] + aB[r];
    }

    f32x4 mm;
    #pragma unroll
    for (int r = 0; r < 4; ++r) mm[r] = fmaxf(fmaxf(l0[r], l1[r]), fmaxf(l2[r], l3[r]));
    zOut = expbits(fmaxf(fmaxf(mm[0], mm[1]), fmaxf(mm[2], mm[3])));

    unsigned long long bal = __ballot(mt > 0);
    if (bal == ~0ull) {
      #pragma unroll
      for (int rti = 0; rti < 2; ++rti)
        #pragma unroll
        for (int r = 0; r < 4; ++r) Pv[rti][r] = acc[rti][r] * c2[rti][r];
    } else {
      #pragma unroll
      for (int rti = 0; rti < 2; ++rti)
        #pragma unroll
        for (int r = 0; r < 4; ++r) {
          float pn = acc[rti][r] * c2[rti][r];
          float po = Pv[rti][r] * s2;       // alpha held: P scales by 2^-Df
          Pv[rti][r] = (mt > 0) ? pn : po;
        }
    }
    nReg += (float)Dfi;

    publish(wr);
    BAR();
  };

  // controller: Df_1 = 7 (maxP0 = 1 -> z = 0)
  int DfA = 7;
  float s2A = __uint_as_float((uint32_t)(127 - 7) << 23);
  f32x4 c2A[2], c2B[2];
  #pragma unroll
  for (int rti = 0; rti < 2; ++rti)
    #pragma unroll
    for (int r = 0; r < 4; ++r) c2A[rti][r] = __expf(r1[rti][r]) * s2A;

  int zCur;
  #pragma unroll 1
  for (int t = 1; t <= Tsz - 3; t += 2) {   // 1,3,...,117
    f32x4 eB[2];
    #pragma unroll
    for (int rti = 0; rti < 2; ++rti)
      #pragma unroll
      for (int r = 0; r < 4; ++r) eB[rti][r] = __expf(rA[rti][r]);  // em_{t+1}
    STEP(t, c2A, s2A, DfA, zCur);
    int DfB = 7 + (zCur >> 2);
    DfB = DfB < -90 ? -90 : (DfB > 110 ? 110 : DfB);
    float s2B = __uint_as_float((uint32_t)(127 - DfB) << 23);
    #pragma unroll
    for (int rti = 0; rti < 2; ++rti)
      #pragma unroll
      for (int r = 0; r < 4; ++r) c2B[rti][r] = eB[rti][r] * s2B;
    if (t + 3 < Tsz) {
      rA[0] = *(const f32x4*)(ep + (size_t)(t + 3) * Ksz);
      rA[1] = *(const f32x4*)(ep + (size_t)(t + 3) * Ksz + 16);
    }

    f32x4 eA[2];
    #pragma unroll
    for (int rti = 0; rti < 2; ++rti)
      #pragma unroll
      for (int r = 0; r < 4; ++r) eA[rti][r] = __expf(rB[rti][r]);  // em_{t+2}
    STEP(t + 1, c2B, s2B, DfB, zCur);
    DfA = 7 + (zCur >> 2);
    DfA = DfA < -90 ? -90 : (DfA > 110 ? 110 : DfA);
    s2A = __uint_as_float((uint32_t)(127 - DfA) << 23);
    #pragma unroll
    for (int rti = 0; rti < 2; ++rti)
      #pragma unroll
      for (int r = 0; r < 4; ++r) c2A[rti][r] = eA[rti][r] * s2A;
    if (t + 4 < Tsz) {
      rB[0] = *(const f32x4*)(ep + (size_t)(t + 4) * Ksz);
      rB[1] = *(const f32x4*)(ep + (size_t)(t + 4) * Ksz + 16);
    }
  }
  STEP(Tsz - 1, c2A, s2A, DfA, zCur);       // t = 119

  // ---- lognorm = nReg*ln2 + ln(sum_col P)
  {
    float ss = ((Pv[0][0] + Pv[0][1]) + (Pv[0][2] + Pv[0][3]))
             + ((Pv[1][0] + Pv[1][1]) + (Pv[1][2] + Pv[1][3]));
    lamp[0][c][slot] = ss;    // buffer 0 dead after last step (wr was 1)
  }
  BAR();
  float lognorm;
  {
    const float* lr = &lamp[0][c][0];
    f32x4 l0 = *(const f32x4*)(lr), l1 = *(const f32x4*)(lr + 4);
    f32x4 l2 = *(const f32x4*)(lr + 8), l3 = *(const f32x4*)(lr + 12);
    float tot = (((l0[0] + l0[1]) + (l0[2] + l0[3]))
              + ((l1[0] + l1[1]) + (l1[2] + l1[3])))
              + (((l2[0] + l2[1]) + (l2[2] + l2[3]))
              + ((l3[0] + l3[1]) + (l3[2] + l3[3])));
    lognorm = nReg * LN2 + __logf(tot);
  }

  // ---- score: slot s covers t in [8s, 8s+8), batch col c
  {
    const int* tb = tag + (size_t)(b0 + c) * Tsz;
    const float* eb2 = emis + (size_t)(b0 + c) * Tsz * Ksz;
    float sc = 0.f;
    const int t0 = 8 * slot;
    const int t1 = (t0 + 8 < Tsz) ? t0 + 8 : Tsz;
    #pragma unroll 1
    for (int t = t0; t < t1; ++t) {
      int tg0 = tb[t];
      float m0 = (float)maskLds[t * 16 + c];
      sc += eb2[(size_t)t * Ksz + tg0] * m0;
      if (t + 1 < Tsz) {
        int tg1 = tb[t + 1];
        sc += Tg[(size_t)tg0 * Ksz + tg1] * m0 * (float)maskLds[(t + 1) * 16 + c];
      }
    }
    float* scb = (float*)&Pb[0][0];   // reuse as [c][16]
    scb[c * 16 + slot] = sc;
    BAR();
    if (tid < 16) {                   // w=0, hi=0, c=tid
      const float* sr = &scb[tid * 16];
      float s2r = 0.f;
      #pragma unroll
      for (int s = 0; s < 16; ++s) s2r += sr[s];
      nll[b0 + tid] = lognorm - s2r;
    }
  }
}

// deterministic fixed-order mean over B values
__global__ __launch_bounds__(256) void crf_reduce(
    const float* __restrict__ nll, float* __restrict__ out) {
  __shared__ float buf[256];
  float s = 0.f;
  for (int i = threadIdx.x; i < Bsz; i += 256) s += nll[i];
  buf[threadIdx.x] = s;
  __syncthreads();
  #pragma unroll
  for (int off = 128; off > 0; off >>= 1) {
    if (threadIdx.x < off) buf[threadIdx.x] += buf[threadIdx.x + off];
    __syncthreads();
  }
  if (threadIdx.x == 0) out[0] = buf[0] / (float)Bsz;
}

extern "C" void kernel_launch(void* const* d_in, const int* in_sizes, int n_in,
                              void* d_out, int out_size, void* d_ws, size_t ws_size,
                              hipStream_t stream) {
  const float* emissions   = (const float*)d_in[0];
  const int*   tag_ids     = (const int*)d_in[1];
  const int*   mask        = (const int*)d_in[2];
  const float* transitions = (const float*)d_in[3];

  float* nll = (float*)d_ws;  // 2048 floats

  crf_fwd<<<Bsz / 16, 256, 0, stream>>>(emissions, tag_ids, mask, transitions, nll);
  crf_reduce<<<1, 256, 0, stream>>>(nll, (float*)d_out);
}